// Round 2
// baseline (232.509 us; speedup 1.0000x reference)
//
#include <hip/hip_runtime.h>
#include <math.h>

// Problem constants (compile-time fixed)
#define NB   2
#define LQ   13294
#define NROWS (NB*LQ)      // 26588
#define CDIM 256

typedef unsigned short u16;
typedef unsigned int   u32;
typedef short bf16x8 __attribute__((ext_vector_type(8)));
typedef float f32x4  __attribute__((ext_vector_type(4)));

struct alignas(8) U16x4 { u16 x, y, z, w; };

__device__ __forceinline__ u16 f2bf(float f) {   // round-to-nearest-even
    u32 u = __builtin_bit_cast(u32, f);
    u += 0x7FFFu + ((u >> 16) & 1u);
    return (u16)(u >> 16);
}
__device__ __forceinline__ float bf2f(u16 h) {
    u32 u = ((u32)h) << 16;
    return __builtin_bit_cast(float, u);
}

__device__ __forceinline__ void gload_lds16(const void* g, void* l) {
    __builtin_amdgcn_global_load_lds(
        (__attribute__((address_space(1))) void*)g,
        (__attribute__((address_space(3))) void*)l, 16, 0, 0);
}

// ONE prep dispatch: cvt query (blocks 0..6646), cvt inflat (6647..13293),
// weights+bias concat (13294..14189).
__global__ __launch_bounds__(256)
void prep_all(const float4* __restrict__ query, const float4* __restrict__ inflat,
              const float* __restrict__ Wv, const float* __restrict__ Woff,
              const float* __restrict__ Wa, const float* __restrict__ Wo,
              const float* __restrict__ boff, const float* __restrict__ ba,
              u16* __restrict__ qb, u16* __restrict__ ib,
              u16* __restrict__ wb, float* __restrict__ biascat) {
    const int b = blockIdx.x;
    const int t = threadIdx.x;
    if (b < 6647) {
        int i = b * 256 + t;
        float4 v = query[i];
        U16x4 o{f2bf(v.x), f2bf(v.y), f2bf(v.z), f2bf(v.w)};
        *(U16x4*)&qb[(size_t)i * 4] = o;
    } else if (b < 13294) {
        int i = (b - 6647) * 256 + t;
        float4 v = inflat[i];
        U16x4 o{f2bf(v.x), f2bf(v.y), f2bf(v.z), f2bf(v.w)};
        *(U16x4*)&ib[(size_t)i * 4] = o;
    } else {
        int i = (b - 13294) * 256 + t;
        float v;
        if      (i <  65536) v = Wv[i];
        else if (i < 131072) v = Woff[i - 65536];
        else if (i < 163840) v = Wa[i - 131072];
        else                 v = Wo[i - 163840];
        wb[i] = f2bf(v);
        if (b == 13294) {
            biascat[t] = boff[t];
            if (t < 128) biascat[256 + t] = ba[t];
        }
    }
}

// m97-structure GEMM core: 128x128 tile, BK=64, 4 K-iterations, 32 KB LDS,
// global_load_lds width-16 direct staging (linear LDS dest + pre-swizzled
// global source; XOR-swizzled ds_read). Wave w owns the 64x64 quadrant
// (w>>1, w&1) as acc[4][4] 16x16 fragments.
__device__ __forceinline__ void gemm_core128(
    const u16* __restrict__ A, const u16* __restrict__ Bw, int M, int row0,
    u16* As, u16* Bs, f32x4 (&acc)[4][4]) {
    const int tid  = threadIdx.x;
    const int lane = tid & 63;
    const int wave = tid >> 6;
    const int ln16 = lane & 15;
    const int kq   = lane >> 4;
    const int wr   = (wave >> 1) * 64;
    const int wc   = (wave & 1) * 64;

    #pragma unroll
    for (int kt = 0; kt < 4; ++kt) {
        const int k0 = kt * 64;
        // stage A(128 rows x 64 k) + B(128 cols x 64 k): 1024 16B chunks each.
        // LDS dest linear: chunk*16B  (= wave-uniform base + lane*16  OK)
        // Global source pre-swizzled: chunk ch reads global chunk ch^(row&7).
        #pragma unroll
        for (int it = 0; it < 4; ++it) {
            int chunk = it * 256 + tid;         // 0..1023
            int row = chunk >> 3;               // 0..127
            int ch  = chunk & 7;                // 16B chunk within 128B row
            int chs = (ch ^ (row & 7)) * 8;     // swizzled source elem offset
            int gra = min(row0 + row, M - 1);
            gload_lds16(A  + (size_t)gra * 256 + k0 + chs, As + chunk * 8);
            gload_lds16(Bw + (size_t)row * 256 + k0 + chs, Bs + chunk * 8);
        }
        __syncthreads();   // compiler emits vmcnt(0) drain before s_barrier
        #pragma unroll
        for (int kf = 0; kf < 2; ++kf) {
            const int ck = kf * 4 + kq;         // chunk index for k = kf*32+kq*8
            bf16x8 a[4], b[4];
            #pragma unroll
            for (int i = 0; i < 4; ++i) {
                int r = wr + i * 16 + ln16;
                a[i] = *(const bf16x8*)&As[r * 64 + ((ck ^ (r & 7)) * 8)];
                int c = wc + i * 16 + ln16;
                b[i] = *(const bf16x8*)&Bs[c * 64 + ((ck ^ (c & 7)) * 8)];
            }
            #pragma unroll
            for (int i = 0; i < 4; ++i)
                #pragma unroll
                for (int j = 0; j < 4; ++j)
                    acc[i][j] = __builtin_amdgcn_mfma_f32_16x16x32_bf16(
                        a[i], b[j], acc[i][j], 0, 0, 0);
        }
        __syncthreads();
    }
}

// Front GEMMs merged, 128-wide strips:
//   s=0,1 -> value = ib@Wv^T+bv (bf16 out, cols s*128..)
//   s=2,3 -> offb  = qb@Woff^T+boff (fp32)
//   s=4   -> logit = qb@Wa^T+ba (fp32)
// B concat [Wv;Woff;Wa] is contiguous in wb: strip s rows at wb + s*32768.
__global__ __launch_bounds__(256, 3)
void gemm_front(const u16* __restrict__ qb, const u16* __restrict__ ib,
                const u16* __restrict__ wb, const float* __restrict__ bv,
                const float* __restrict__ bcat, u16* __restrict__ value,
                float* __restrict__ offb, float* __restrict__ logit, int M) {
    __shared__ u16 As[128 * 64];
    __shared__ u16 Bs[128 * 64];
    const int s    = blockIdx.x;          // 0..4
    const int row0 = blockIdx.y * 128;
    const u16* A  = (s < 2) ? ib : qb;
    const u16* Bw = wb + (size_t)s * 32768;
    const float* bias = (s < 2) ? bv + s * 128 : bcat + (s - 2) * 128;

    f32x4 acc[4][4] = {};
    gemm_core128(A, Bw, M, row0, As, Bs, acc);

    const int lane = threadIdx.x & 63;
    const int wave = threadIdx.x >> 6;
    const int ln16 = lane & 15, kq = lane >> 4;
    const int wr = (wave >> 1) * 64, wc = (wave & 1) * 64;
    #pragma unroll
    for (int j = 0; j < 4; ++j) {
        int lc = wc + j * 16 + ln16;      // 0..127 within strip
        float bj = bias[lc];
        #pragma unroll
        for (int i = 0; i < 4; ++i) {
            #pragma unroll
            for (int r = 0; r < 4; ++r) {
                int gr = row0 + wr + i * 16 + kq * 4 + r;
                if (gr < M) {
                    float o = acc[i][j][r] + bj;
                    if (s < 2)
                        value[(size_t)gr * 256 + s * 128 + lc] = f2bf(o);
                    else if (s < 4)
                        offb[(size_t)gr * 256 + (s - 2) * 128 + lc] = o;
                    else
                        logit[(size_t)gr * 128 + lc] = o;
                }
            }
        }
    }
}

// out = tmp @ Wo^T + bo (fp32, ld 256), strips 0..1 (128 cols each)
__global__ __launch_bounds__(256, 3)
void gemm_out(const u16* __restrict__ A, const u16* __restrict__ Bw0,
              const float* __restrict__ bias, float* __restrict__ C, int M) {
    __shared__ u16 As[128 * 64];
    __shared__ u16 Bs[128 * 64];
    const int s    = blockIdx.x;
    const int row0 = blockIdx.y * 128;
    const u16* Bw = Bw0 + (size_t)s * 32768;

    f32x4 acc[4][4] = {};
    gemm_core128(A, Bw, M, row0, As, Bs, acc);

    const int lane = threadIdx.x & 63;
    const int wave = threadIdx.x >> 6;
    const int ln16 = lane & 15, kq = lane >> 4;
    const int wr = (wave >> 1) * 64, wc = (wave & 1) * 64;
    #pragma unroll
    for (int j = 0; j < 4; ++j) {
        int gc = s * 128 + wc + j * 16 + ln16;
        float bj = bias[gc];
        #pragma unroll
        for (int i = 0; i < 4; ++i) {
            #pragma unroll
            for (int r = 0; r < 4; ++r) {
                int gr = row0 + wr + i * 16 + kq * 4 + r;
                if (gr < M) C[(size_t)gr * 256 + gc] = acc[i][j][r] + bj;
            }
        }
    }
}

// Sampler: 4 queries/block, 3 phases (softmax / 512 point-descriptors /
// gather). value is bf16 (halved working set + gather bytes).
__global__ __launch_bounds__(256)
void msda_sample(const u16* __restrict__ value,     // (NB*LQ, 256) bf16
                 const float* __restrict__ refpts,  // (NB*LQ, 4, 2)
                 const float* __restrict__ off,     // (NB*LQ, 256) fp32
                 const float* __restrict__ logits,  // (NB*LQ, 128) fp32
                 u16* __restrict__ tmp) {           // (NB*LQ, 256) bf16
    __shared__ float sAw[4][8][16];
    __shared__ int   sLin[4][8][17][4];
    __shared__ float sW[4][8][17][4];

    const int t  = threadIdx.x;
    const int qb = blockIdx.x * 4;

    // ---- Phase A: softmax per (q,m) ----
    if (t < 32) {
        const int qi = t >> 3, m = t & 7;
        const float* lg = logits + (size_t)(qb + qi) * 128 + m * 16;
        float e[16];
        float mx = -1e30f;
        #pragma unroll
        for (int i = 0; i < 16; ++i) { e[i] = lg[i]; mx = fmaxf(mx, e[i]); }
        float s = 0.f;
        #pragma unroll
        for (int i = 0; i < 16; ++i) { e[i] = __expf(e[i] - mx); s += e[i]; }
        const float inv = 1.f / s;
        #pragma unroll
        for (int i = 0; i < 16; ++i) sAw[qi][m][i] = e[i] * inv;
    }
    __syncthreads();

    // ---- Phase B: 512 point jobs, 2 per thread ----
    #pragma unroll
    for (int j2 = 0; j2 < 2; ++j2) {
        const int job = t + j2 * 256;
        const int qi = job >> 7;
        const int m  = (job >> 4) & 7;
        const int p  = job & 15;
        const int l  = p >> 2, pp = p & 3;
        const int q  = qb + qi;
        const int n  = (q >= LQ) ? 1 : 0;

        const int W = (l == 0) ? 100 : (l == 1) ? 50 : (l == 2) ? 25 : 13;
        const int H = W;
        const int st = (l == 0) ? 0 : (l == 1) ? 10000 : (l == 2) ? 12500 : 13125;

        const float rx = refpts[(size_t)q * 8 + l * 2 + 0];
        const float ry = refpts[(size_t)q * 8 + l * 2 + 1];
        const float ox = off[(size_t)q * 256 + m * 32 + (l * 4 + pp) * 2 + 0];
        const float oy = off[(size_t)q * 256 + m * 32 + (l * 4 + pp) * 2 + 1];

        // replicate reference arithmetic order
        const float locx = rx + ox / (float)W;
        const float locy = ry + oy / (float)H;
        const float grx = 2.f * locx - 1.f;
        const float gry = 2.f * locy - 1.f;
        const float gx = ((grx + 1.f) * (float)W - 1.f) * 0.5f;
        const float gy = ((gry + 1.f) * (float)H - 1.f) * 0.5f;
        const float x0f = floorf(gx), y0f = floorf(gy);
        const float fx = gx - x0f, fy = gy - y0f;
        const int x0 = (int)x0f, y0 = (int)y0f;
        const int x1 = x0 + 1, y1 = y0 + 1;

        const int cx0 = min(max(x0, 0), W - 1);
        const int cx1 = min(max(x1, 0), W - 1);
        const int cy0 = min(max(y0, 0), H - 1);
        const int cy1 = min(max(y1, 0), H - 1);
        const bool vx0 = (x0 >= 0) & (x0 < W);
        const bool vx1 = (x1 >= 0) & (x1 < W);
        const bool vy0 = (y0 >= 0) & (y0 < H);
        const bool vy1 = (y1 >= 0) & (y1 < H);

        const float aw = sAw[qi][m][p];
        const int base = n * LQ + st;
        sLin[qi][m][p][0] = base + cy0 * W + cx0;
        sLin[qi][m][p][1] = base + cy0 * W + cx1;
        sLin[qi][m][p][2] = base + cy1 * W + cx0;
        sLin[qi][m][p][3] = base + cy1 * W + cx1;
        sW[qi][m][p][0] = (vy0 & vx0) ? aw * (1.f - fy) * (1.f - fx) : 0.f;
        sW[qi][m][p][1] = (vy0 & vx1) ? aw * (1.f - fy) * fx         : 0.f;
        sW[qi][m][p][2] = (vy1 & vx0) ? aw * fy * (1.f - fx)         : 0.f;
        sW[qi][m][p][3] = (vy1 & vx1) ? aw * fy * fx                 : 0.f;
    }
    __syncthreads();

    // ---- Phase C: gather (batched 4 points = 16 loads in flight) ----
    const int qi = t >> 6;
    const int m  = (t >> 3) & 7;
    const int e  = t & 7;
    const int q  = qb + qi;
    const u16* vch = value + m * 32 + e * 4;

    float ax = 0.f, ay = 0.f, az = 0.f, aw_ = 0.f;
    #pragma unroll
    for (int g = 0; g < 4; ++g) {
        U16x4 raw[16];
        float4 Wt4[4];
        #pragma unroll
        for (int pp = 0; pp < 4; ++pp) {
            int p = g * 4 + pp;
            int4 L = *(const int4*)&sLin[qi][m][p][0];
            Wt4[pp] = *(const float4*)&sW[qi][m][p][0];
            raw[pp * 4 + 0] = *(const U16x4*)(vch + (size_t)L.x * 256);
            raw[pp * 4 + 1] = *(const U16x4*)(vch + (size_t)L.y * 256);
            raw[pp * 4 + 2] = *(const U16x4*)(vch + (size_t)L.z * 256);
            raw[pp * 4 + 3] = *(const U16x4*)(vch + (size_t)L.w * 256);
        }
        #pragma unroll
        for (int pp = 0; pp < 4; ++pp) {
            const float* wp = (const float*)&Wt4[pp];
            #pragma unroll
            for (int c = 0; c < 4; ++c) {
                U16x4 r = raw[pp * 4 + c];
                float wgt = wp[c];
                ax  += wgt * bf2f(r.x);
                ay  += wgt * bf2f(r.y);
                az  += wgt * bf2f(r.z);
                aw_ += wgt * bf2f(r.w);
            }
        }
    }
    U16x4 o{f2bf(ax), f2bf(ay), f2bf(az), f2bf(aw_)};
    *(U16x4*)&tmp[(size_t)q * 256 + m * 32 + e * 4] = o;
}

extern "C" void kernel_launch(void* const* d_in, const int* in_sizes, int n_in,
                              void* d_out, int out_size, void* d_ws, size_t ws_size,
                              hipStream_t stream) {
    const float* query  = (const float*)d_in[0];
    const float* refpts = (const float*)d_in[1];
    const float* inflat = (const float*)d_in[2];
    const float* Wv   = (const float*)d_in[5];
    const float* bv   = (const float*)d_in[6];
    const float* Woff = (const float*)d_in[7];
    const float* boff = (const float*)d_in[8];
    const float* Wa   = (const float*)d_in[9];
    const float* ba   = (const float*)d_in[10];
    const float* Wo   = (const float*)d_in[11];
    const float* bo   = (const float*)d_in[12];
    float* out = (float*)d_out;

    // workspace layout (~82 MB)
    char* ws = (char*)d_ws;
    constexpr size_t SZ16 = (size_t)NROWS * 256 * 2;   // 13,613,056
    constexpr size_t SZ32 = (size_t)NROWS * 256 * 4;   // 27,226,112
    constexpr size_t SZL  = (size_t)NROWS * 128 * 4;   // 13,613,056
    u16*   qb    = (u16*)(ws);                         // bf16 query; later tmp
    u16*   ib    = (u16*)(ws + SZ16);                  // bf16 input
    u16*   value = (u16*)(ws + 2 * SZ16);              // bf16 value
    float* offb  = (float*)(ws + 3 * SZ16);            // fp32
    float* logit = (float*)(ws + 3 * SZ16 + SZ32);     // fp32
    u16*   wb    = (u16*)(ws + 3 * SZ16 + SZ32 + SZL); // bf16 weights
    float* bcat  = (float*)(ws + 3 * SZ16 + SZ32 + SZL + 229376 * 2);
    u16*   tmp   = qb;

    const int RG = (NROWS + 127) / 128;   // 208 row-groups

    hipLaunchKernelGGL(prep_all, dim3(14190), dim3(256), 0, stream,
                       (const float4*)query, (const float4*)inflat,
                       Wv, Woff, Wa, Wo, boff, ba, qb, ib, wb, bcat);

    gemm_front<<<dim3(5, RG), dim3(256), 0, stream>>>(
        qb, ib, wb, bv, bcat, value, offb, logit, NROWS);

    hipLaunchKernelGGL(msda_sample, dim3(NROWS / 4), dim3(256), 0, stream,
                       value, refpts, offb, logit, tmp);

    gemm_out<<<dim3(2, RG), dim3(256), 0, stream>>>(
        tmp, wb + 163840, bo, out, NROWS);
}